// Round 9
// baseline (707.643 us; speedup 1.0000x reference)
//
#include <hip/hip_runtime.h>

#define S     512
#define NOBS  1024
#define TT    512
#define CH    16     // chains per workgroup (= MFMA N)
#define NWAVE 8
#define NJT   4      // j-tiles (16 rows) per wave: 8*4 = 32 tiles = 512 rows
#define NGRP  4

typedef __attribute__((ext_vector_type(4))) float f32x4;
typedef __attribute__((ext_vector_type(4))) int   i32x4;
typedef __attribute__((ext_vector_type(8))) int   i32x8;
typedef __attribute__((ext_vector_type(2))) unsigned int u32x2;
typedef long i64;

__device__ __forceinline__ unsigned short f2bf(float x) {
  unsigned u = __builtin_bit_cast(unsigned, x);
  return (unsigned short)((u + 0x7fffu + ((u >> 16) & 1u)) >> 16);  // RNE
}
__device__ __forceinline__ float bflo(unsigned u) {       // bf16 low half -> f32
  return __builtin_bit_cast(float, u << 16);
}
__device__ __forceinline__ float bfhi_raw(unsigned u) {   // bf16 high half, low-mantissa garbage (<=2^-7 rel)
  return __builtin_bit_cast(float, u);
}
__device__ __forceinline__ float bfhi(unsigned u) {
  return __builtin_bit_cast(float, u & 0xffff0000u);
}

__device__ __forceinline__ unsigned char f2fp8_sw(float x) {
  x = fminf(fmaxf(x, 0.f), 448.f);
  unsigned u = __builtin_bit_cast(unsigned, x);
  int ex = (int)((u >> 23) & 0xff);
  if (ex >= 121) {
    unsigned m = (u & 0x7fffff) | 0x800000;
    unsigned keep = m >> 20, rest = m & 0xfffff;
    keep += (rest > 0x80000u) || (rest == 0x80000u && (keep & 1));
    int e8 = ex - 127 + 7;
    if (keep == 16) { keep = 8; e8++; }
    if (e8 >= 16) return 0x7e;
    return (unsigned char)((e8 << 3) | (keep & 7));
  } else {
    int m = (int)(x * 512.0f + 0.5f);
    if (m > 8) m = 8;
    return (unsigned char)m;
  }
}

__device__ __forceinline__ unsigned pack4_fp8(float p0, float p1, float p2, float p3) {
#if __has_builtin(__builtin_amdgcn_cvt_pk_fp8_f32)
  int v = __builtin_amdgcn_cvt_pk_fp8_f32(p0, p1, 0, false);
  v = __builtin_amdgcn_cvt_pk_fp8_f32(p2, p3, v, true);
  return (unsigned)v;
#else
  return (unsigned)f2fp8_sw(p0) | ((unsigned)f2fp8_sw(p1) << 8) |
         ((unsigned)f2fp8_sw(p2) << 16) | ((unsigned)f2fp8_sw(p3) << 24);
#endif
}

__device__ __forceinline__ float wave_max(float v) {
  for (int d = 32; d; d >>= 1) v = fmaxf(v, __shfl_xor(v, d));
  return v;
}
__device__ __forceinline__ float wave_sum(float v) {
  for (int d = 32; d; d >>= 1) v += __shfl_xor(v, d);
  return v;
}

// ---- log_pi log-softmax ----
__global__ void prep_pi(const float* __restrict__ log_pi, float* __restrict__ lpi) {
  const int l = threadIdx.x;
  float v[8];
  float mx = -INFINITY;
  for (int k = 0; k < 8; ++k) { v[k] = log_pi[l + 64 * k]; mx = fmaxf(mx, v[k]); }
  mx = wave_max(mx);
  float sm = 0.f;
  for (int k = 0; k < 8; ++k) sm += __expf(v[k] - mx);
  sm = wave_sum(sm);
  const float lse = mx + __logf(sm);
  for (int k = 0; k < 8; ++k) lpi[l + 64 * k] = v[k] - lse;
}

// ---- log_B row log-softmax -> bf16 transposed: Bexp16[o*S + j] ----
__global__ void prep_B(const float* __restrict__ log_B, unsigned short* __restrict__ Bexp16) {
  const int j = blockIdx.x, l = threadIdx.x;
  const float* row = log_B + (size_t)j * NOBS;
  float v[16];
  float mx = -INFINITY;
  for (int k = 0; k < 16; ++k) { v[k] = row[l + 64 * k]; mx = fmaxf(mx, v[k]); }
  mx = wave_max(mx);
  float sm = 0.f;
  for (int k = 0; k < 16; ++k) sm += __expf(v[k] - mx);
  sm = wave_sum(sm);
  const float lse = mx + __logf(sm);
  for (int k = 0; k < 16; ++k) Bexp16[(size_t)(l + 64 * k) * S + j] = f2bf(__expf(v[k] - lse));
}

// ---- log_A row log-softmax -> fp8 e4m3, K=128-chunk fragment order ----
// Afrag8[ ((jt*4 + c)*64 + lane)*32 + e ] = Aexp[i = c*128 + (lane>>4)*32 + e][j = jt*16 + (lane&15)]
__global__ void prep_A(const float* __restrict__ log_A, unsigned char* __restrict__ Afrag8) {
  const int i = blockIdx.x, l = threadIdx.x;
  const float* row = log_A + (size_t)i * S;
  float v[8];
  float mx = -INFINITY;
  for (int k = 0; k < 8; ++k) { v[k] = row[l + 64 * k]; mx = fmaxf(mx, v[k]); }
  mx = wave_max(mx);
  float sm = 0.f;
  for (int k = 0; k < 8; ++k) sm += __expf(v[k] - mx);
  sm = wave_sum(sm);
  const float lse = mx + __logf(sm);
  const int c = i >> 7, g4s = (i >> 5) & 3, e = i & 31;
  for (int k = 0; k < 8; ++k) {
    const int j = l + 64 * k;
    const int jt = j >> 4, jc = j & 15;
    Afrag8[((size_t)(jt * 4 + c) * 64 + g4s * 16 + jc) * 32 + e] = f2fp8_sw(__expf(v[k] - lse));
  }
}

// P LDS swizzle (within one 8 KB buffer): row m (chain), 16B granule g
__device__ __forceinline__ int pswz(int m, int g) { return m * 512 + (((g ^ m) & 31) << 4); }

__device__ __forceinline__ float max8(const float* p) {
  const f32x4 p0 = *reinterpret_cast<const f32x4*>(p);
  const f32x4 p1 = *reinterpret_cast<const f32x4*>(p + 4);
  return fmaxf(fmaxf(fmaxf(p0[0], p0[1]), fmaxf(p0[2], p0[3])),
               fmaxf(fmaxf(p1[0], p1[1]), fmaxf(p1[2], p1[3])));
}
__device__ __forceinline__ float sum8(const float* p) {
  const f32x4 p0 = *reinterpret_cast<const f32x4*>(p);
  const f32x4 p1 = *reinterpret_cast<const f32x4*>(p + 4);
  return ((p0[0] + p0[1]) + (p0[2] + p0[3])) + ((p1[0] + p1[1]) + (p1[2] + p1[3]));
}

// one K=128 chunk MFMA (scale = 1.0)
__device__ __forceinline__ f32x4 mfma_chunk(const i32x8 a, const i32x8 b, f32x4 acc) {
#if __has_builtin(__builtin_amdgcn_mfma_scale_f32_16x16x128_f8f6f4)
  return __builtin_amdgcn_mfma_scale_f32_16x16x128_f8f6f4(
             a, b, acc, 0, 0, 0, 0x7f7f7f7f, 0, 0x7f7f7f7f);
#else
  const i64* pa = reinterpret_cast<const i64*>(&a);
  const i64* pb = reinterpret_cast<const i64*>(&b);
  #pragma unroll
  for (int q = 0; q < 4; ++q)
    acc = __builtin_amdgcn_mfma_f32_16x16x32_fp8_fp8(pa[q], pb[q], acc, 0, 0, 0);
  return acc;
#endif
}

// epilogue for one tile: q = acc * emit * 2^-s ; fp8-pack ; LDS write ; vmax
#define EPI_TILE(JI, ACCP, EB, PW2, PCUR, VMAX) {                                \
  const float q0 = ACCP[JI][0] * (bflo(EB[JI][0]) * (PW2));                      \
  const float q1 = ACCP[JI][1] * (bfhi_raw(EB[JI][0]) * (PW2));                  \
  const float q2 = ACCP[JI][2] * (bflo(EB[JI][1]) * (PW2));                      \
  const float q3 = ACCP[JI][3] * (bfhi_raw(EB[JI][1]) * (PW2));                  \
  *reinterpret_cast<unsigned*>((PCUR) + wr[JI]) = pack4_fp8(q0, q1, q2, q3);     \
  VMAX = fmaxf(fmaxf(VMAX, fmaxf(fmaxf(q0, q1), q2)), q3);                       \
}

#define MFMA_CHUNK_ACC(C, ACCN, PCUR, FIRST) {                                   \
  i32x8 af;                                                                      \
  i32x4* h = reinterpret_cast<i32x4*>(&af);                                      \
  h[0] = *reinterpret_cast<const i32x4*>((PCUR) + rd[C][0]);                     \
  h[1] = *reinterpret_cast<const i32x4*>((PCUR) + rd[C][1]);                     \
  _Pragma("unroll")                                                              \
  for (int ji_ = 0; ji_ < NJT; ++ji_)                                            \
    ACCN[ji_] = mfma_chunk(a_frags[ji_][C], af,                                  \
                           (FIRST) ? f32x4{0.f, 0.f, 0.f, 0.f} : ACCN[ji_]);     \
}

#define PREFETCH_EB(EB, T1) {                                                    \
  const int ob_ = obs_s[mm][T1];                                                 \
  const unsigned short* bp_ = Bexp16 + ((size_t)ob_ << 9) + g4 * 4 + w * 16;     \
  _Pragma("unroll")                                                              \
  for (int ji_ = 0; ji_ < NJT; ++ji_)                                            \
    EB[ji_] = *reinterpret_cast<const u32x2*>(bp_ + ji_ * 128);                  \
}

// one steady iteration: finish step T (epilogue from ACCP) + MFMA for T+1 (into ACCN)
#define STEADY_BODY(T, ACCP, ACCN, EBA, EBB) {                                   \
  unsigned char* __restrict__ pcur = Pb[(T) & 1];                                \
  /* phase 0: predictor + tile0 epilogue */                                      \
  const float pm_ = max8(&pred[((T) - 1) & 1][mm][0]);                           \
  const float en_ = ((T) == 2) ? 0.f : __log2f(pm_);                             \
  const float dr_ = fminf(fmaxf(en_ - e1p, -3.0f), 3.0f);                        \
  int s_ = (int)__builtin_rintf(Lp + en_ + dr_);                                 \
  s_ = min(max(s_, -60), 60);                                                    \
  Lp = (float)s_; e1p = en_; lsc_i += s_;                                        \
  const float pw2_ = __builtin_bit_cast(float, (unsigned)(127 - s_) << 23);      \
  float vmax_ = 0.f;                                                             \
  EPI_TILE(0, ACCP, EBA, pw2_, pcur, vmax_);                                     \
  __syncthreads();                                                               \
  MFMA_CHUNK_ACC(0, ACCN, pcur, true);                                           \
  /* phase 1 */                                                                  \
  EPI_TILE(1, ACCP, EBA, pw2_, pcur, vmax_);                                     \
  __syncthreads();                                                               \
  MFMA_CHUNK_ACC(1, ACCN, pcur, false);                                          \
  /* phase 2 */                                                                  \
  EPI_TILE(2, ACCP, EBA, pw2_, pcur, vmax_);                                     \
  __syncthreads();                                                               \
  PREFETCH_EB(EBB, (T) + 1);                                                     \
  MFMA_CHUNK_ACC(2, ACCN, pcur, false);                                          \
  /* phase 3 */                                                                  \
  EPI_TILE(3, ACCP, EBA, pw2_, pcur, vmax_);                                     \
  vmax_ = fmaxf(vmax_, __shfl_xor(vmax_, 16));                                   \
  vmax_ = fmaxf(vmax_, __shfl_xor(vmax_, 32));                                   \
  if (g4 == 0) pred[(T) & 1][mm][w] = vmax_;                                     \
  __syncthreads();                                                               \
  MFMA_CHUNK_ACC(3, ACCN, pcur, false);                                          \
}

// ---- main: 8 waves, 4-phase in-step pipeline (epilogue_t overlaps MFMA_{t+1}) ----
__global__ __launch_bounds__(512, 2)
void hmm_main(const int* __restrict__ obs, const float* __restrict__ lpi,
              const unsigned short* __restrict__ Bexp16,
              const unsigned char* __restrict__ Afrag8, float* __restrict__ parts)
{
  __shared__ __align__(16) unsigned char Pb[2][CH * S];   // 16 KB fp8, double-buffered
  __shared__ int obs_s[CH][TT + 1];
  __shared__ __align__(16) float pred[2][CH][12];

  const int tid = threadIdx.x;
  const int w = tid >> 6, l = tid & 63, g4 = l >> 4, mm = l & 15;
  const int grp = blockIdx.x;

  // persistent Aexp fragments (AGPR-parked): 128 regs, straight chunk order
  i32x8 a_frags[NJT][4];
  #pragma unroll
  for (int ji = 0; ji < NJT; ++ji) {
    const int jt = w + NWAVE * ji;
    #pragma unroll
    for (int c = 0; c < 4; ++c)
      a_frags[ji][c] = *reinterpret_cast<const i32x8*>(
          Afrag8 + ((size_t)(jt * 4 + c) * 64 + l) * 32);
  }

  // hoisted LDS byte offsets
  int rd[4][2], wr[NJT];
  #pragma unroll
  for (int c = 0; c < 4; ++c) {
    const int g0 = c * 8 + g4 * 2;
    rd[c][0] = pswz(mm, g0);
    rd[c][1] = pswz(mm, g0 + 1);
  }
  #pragma unroll
  for (int ji = 0; ji < NJT; ++ji) wr[ji] = pswz(mm, w + NWAVE * ji) + g4 * 4;

  for (int m = 0; m < CH; ++m)
    obs_s[m][tid] = obs[(size_t)(grp * CH + m) * TT + tid];
  __syncthreads();

  float lsc_f;      // exact log contributions (t0, t1)
  int   lsc_i = 0;  // sum of applied integer log2 scales
  float Lp, e1p;    // predictor state (log2 domain)

  // ---------------- t = 0 (log domain, exact) ----------------
  {
    const int o0 = obs_s[mm][0];
    f32x4 vals[NJT];
    #pragma unroll
    for (int ji = 0; ji < NJT; ++ji) {
      const int j0 = (w + NWAVE * ji) * 16 + g4 * 4;
      const f32x4 lp = *reinterpret_cast<const f32x4*>(lpi + j0);
      const u32x2 e = *reinterpret_cast<const u32x2*>(Bexp16 + (size_t)o0 * S + j0);
      vals[ji][0] = lp[0] + __logf(bflo(e[0]));
      vals[ji][1] = lp[1] + __logf(bfhi(e[0]));
      vals[ji][2] = lp[2] + __logf(bflo(e[1]));
      vals[ji][3] = lp[3] + __logf(bfhi(e[1]));
    }
    float v = -INFINITY;
    #pragma unroll
    for (int ji = 0; ji < NJT; ++ji)
      v = fmaxf(v, fmaxf(fmaxf(vals[ji][0], vals[ji][1]), fmaxf(vals[ji][2], vals[ji][3])));
    v = fmaxf(v, __shfl_xor(v, 16));
    v = fmaxf(v, __shfl_xor(v, 32));
    if (g4 == 0) pred[0][mm][w] = v;
    __syncthreads();
    const float M0 = max8(&pred[0][mm][0]);
    #pragma unroll
    for (int ji = 0; ji < NJT; ++ji)
      *reinterpret_cast<unsigned*>(&Pb[0][wr[ji]]) =
          pack4_fp8(__expf(vals[ji][0] - M0), __expf(vals[ji][1] - M0),
                    __expf(vals[ji][2] - M0), __expf(vals[ji][3] - M0));
    lsc_f = M0;
    __syncthreads();
  }

  // ---------------- t = 1 (linear, exact) ----------------
  {
    const int o1 = obs_s[mm][1];
    u32x2 eb1[NJT];
    const unsigned short* bp = Bexp16 + ((size_t)o1 << 9) + g4 * 4 + w * 16;
    #pragma unroll
    for (int ji = 0; ji < NJT; ++ji)
      eb1[ji] = *reinterpret_cast<const u32x2*>(bp + ji * 128);

    f32x4 acc[NJT];
    MFMA_CHUNK_ACC(0, acc, Pb[0], true);
    MFMA_CHUNK_ACC(1, acc, Pb[0], false);
    MFMA_CHUNK_ACC(2, acc, Pb[0], false);
    MFMA_CHUNK_ACC(3, acc, Pb[0], false);

    f32x4 vals[NJT];
    #pragma unroll
    for (int ji = 0; ji < NJT; ++ji) {
      vals[ji][0] = acc[ji][0] * bflo(eb1[ji][0]);
      vals[ji][1] = acc[ji][1] * bfhi(eb1[ji][0]);
      vals[ji][2] = acc[ji][2] * bflo(eb1[ji][1]);
      vals[ji][3] = acc[ji][3] * bfhi(eb1[ji][1]);
    }
    float v = -INFINITY;
    #pragma unroll
    for (int ji = 0; ji < NJT; ++ji)
      v = fmaxf(v, fmaxf(fmaxf(vals[ji][0], vals[ji][1]), fmaxf(vals[ji][2], vals[ji][3])));
    v = fmaxf(v, __shfl_xor(v, 16));
    v = fmaxf(v, __shfl_xor(v, 32));
    if (g4 == 0) pred[1][mm][w] = v;
    __syncthreads();
    const float v1 = max8(&pred[1][mm][0]);
    const float inv = __builtin_amdgcn_rcpf(v1);
    lsc_f += __logf(v1);
    Lp = __log2f(v1); e1p = 0.f;
    #pragma unroll
    for (int ji = 0; ji < NJT; ++ji)
      *reinterpret_cast<unsigned*>(&Pb[1][wr[ji]]) =
          pack4_fp8(vals[ji][0] * inv, vals[ji][1] * inv,
                    vals[ji][2] * inv, vals[ji][3] * inv);
    __syncthreads();
  }

  // ---------------- pipeline prologue: acc for t=2, eb for t=2 ----------------
  f32x4 accA[NJT], accB[NJT];
  u32x2 ebA[NJT], ebB[NJT];
  PREFETCH_EB(ebA, 2);
  MFMA_CHUNK_ACC(0, accA, Pb[1], true);
  MFMA_CHUNK_ACC(1, accA, Pb[1], false);
  MFMA_CHUNK_ACC(2, accA, Pb[1], false);
  MFMA_CHUNK_ACC(3, accA, Pb[1], false);

  // ---------------- steady: finish t = 2 .. 510 ----------------
  for (int t = 2; t < 510; t += 2) {
    STEADY_BODY(t,     accA, accB, ebA, ebB);
    STEADY_BODY(t + 1, accB, accA, ebB, ebA);
  }
  STEADY_BODY(510, accA, accB, ebA, ebB);

  // ---------------- t = 511 (final: sum; acc already in accB, emit in ebB) ----------------
  {
    const float pm = max8(&pred[0][mm][0]);
    const float e_new = __log2f(pm);
    const float dsr = fminf(fmaxf(e_new - e1p, -3.0f), 3.0f);
    int s = (int)__builtin_rintf(Lp + e_new + dsr);
    s = min(max(s, -60), 60);
    lsc_i += s;
    const float pw2 = __builtin_bit_cast(float, (unsigned)(127 - s) << 23);

    float ssum = 0.f;
    #pragma unroll
    for (int ji = 0; ji < NJT; ++ji)
      ssum += accB[ji][0] * bflo(ebB[ji][0]) + accB[ji][1] * bfhi(ebB[ji][0]) +
              accB[ji][2] * bflo(ebB[ji][1]) + accB[ji][3] * bfhi(ebB[ji][1]);
    ssum *= pw2;
    ssum += __shfl_xor(ssum, 16);
    ssum += __shfl_xor(ssum, 32);
    if (g4 == 0) pred[1][mm][w] = ssum;
    __syncthreads();
    if (w == 0 && g4 == 0) {
      const float s8 = sum8(&pred[1][mm][0]);
      float cl = lsc_f + (float)lsc_i * 0.69314718056f + __logf(s8);
      for (int d = 1; d < 16; d <<= 1) cl += __shfl_xor(cl, d);
      if (l == 0) parts[grp] = cl;
    }
  }
}

__global__ void final_sum(const float* __restrict__ parts, float* __restrict__ out) {
  out[0] = parts[0] + parts[1] + parts[2] + parts[3];
}

extern "C" void kernel_launch(void* const* d_in, const int* in_sizes, int n_in,
                              void* d_out, int out_size, void* d_ws, size_t ws_size,
                              hipStream_t stream) {
  const int*   obs  = (const int*)d_in[0];
  const float* lgpi = (const float*)d_in[1];
  const float* lgA  = (const float*)d_in[2];
  const float* lgB  = (const float*)d_in[3];
  float* out = (float*)d_out;

  char* ws = (char*)d_ws;
  unsigned short* Bexp16 = (unsigned short*)ws;                          // 1 MB
  unsigned char*  Afrag8 = (unsigned char*)(ws + (size_t)NOBS * S * 2);  // 256 KB
  float*          lpi    = (float*)(ws + (size_t)NOBS * S * 2 + (size_t)S * S);
  float*          parts  = lpi + S;

  prep_pi<<<1, 64, 0, stream>>>(lgpi, lpi);
  prep_B<<<S, 64, 0, stream>>>(lgB, Bexp16);
  prep_A<<<S, 64, 0, stream>>>(lgA, Afrag8);
  hmm_main<<<NGRP, 512, 0, stream>>>(obs, lpi, Bexp16, Afrag8, parts);
  final_sum<<<1, 1, 0, stream>>>(parts, out);
}